// Round 7
// baseline (1079.390 us; speedup 1.0000x reference)
//
#include <hip/hip_runtime.h>

// ---------------------------------------------------------------------------
// GINE edge model. Round 7: (1) k_edge1 LE-via-MFMA (kills VALU A-stage),
// (2) fused node-centric conv2 (no atomics/memset/agg2 traffic),
// (3) dst-sorted k_head with ep scatter.
// ---------------------------------------------------------------------------

using f32x4 = __attribute__((ext_vector_type(4))) float;
using s16x8 = __attribute__((ext_vector_type(8))) short;

#define N_NODES 100000
#define N_EDGES 600000
#define NODE_IN 387
#define KPAD    416   // 13 * 32
#define HID     128
#define NB_SCAN 391   // ceil(100000/256)

__device__ __forceinline__ unsigned short f2bf(float f) {
    unsigned u = __float_as_uint(f);
    u += 0x7FFFu + ((u >> 16) & 1u);   // RNE
    return (unsigned short)(u >> 16);
}
__device__ __forceinline__ float bf2f(short h) {
    return __uint_as_float(((unsigned)(unsigned short)h) << 16);
}

// --------------------------- edge_index decode -----------------------------
__global__ __launch_bounds__(256) void k_decode(const unsigned* __restrict__ w,
                                                int* __restrict__ s32,
                                                int* __restrict__ d32) {
    __shared__ unsigned long long bs[4];
    __shared__ int is64_s;
    const int t = threadIdx.x;
    unsigned any = 0;
    for (int i = 1 + 2 * t; i < 2048; i += 512) any |= w[i];
    unsigned long long b = __ballot(any != 0);
    if ((t & 63) == 0) bs[t >> 6] = b;
    __syncthreads();
    if (t == 0) is64_s = ((bs[0] | bs[1] | bs[2] | bs[3]) == 0ULL) ? 1 : 0;
    __syncthreads();
    const int is64 = is64_s;
    const int e = blockIdx.x * 256 + t;
    if (e < N_EDGES) {
        if (is64) {
            s32[e] = (int)w[2 * e];
            d32[e] = (int)w[2 * N_EDGES + 2 * e];
        } else {
            s32[e] = (int)w[e];
            d32[e] = (int)w[N_EDGES + e];
        }
    }
}

// ------------------------ weight transpose + bf16 --------------------------
// adds E1T[416][32]: E1T[f][q] = e1w[q][f] (q<7), e1b[f] (q==7), 0 else.
__global__ __launch_bounds__(256) void k_prep(const float* __restrict__ w1,
                                              const float* __restrict__ w2,
                                              const float* __restrict__ v1,
                                              const float* __restrict__ v2,
                                              const float* __restrict__ ew1,
                                              const float* __restrict__ e1w,
                                              const float* __restrict__ e1b,
                                              unsigned short* __restrict__ W1t,
                                              unsigned short* __restrict__ W2t,
                                              unsigned short* __restrict__ V1t,
                                              unsigned short* __restrict__ V2t,
                                              unsigned short* __restrict__ EW1t,
                                              unsigned short* __restrict__ E1T) {
    int i = blockIdx.x * 256 + threadIdx.x;
    if (i < 128 * KPAD) {
        int c = i / KPAD, k = i - c * KPAD;
        W1t[i] = (k < NODE_IN) ? f2bf(w1[k * HID + c]) : (unsigned short)0;
        return;
    }
    i -= 128 * KPAD;
    if (i < 16384) { int c = i >> 7, k = i & 127; W2t[i] = f2bf(w2[k * HID + c]); return; }
    i -= 16384;
    if (i < 16384) { int c = i >> 7, k = i & 127; V1t[i] = f2bf(v1[k * HID + c]); return; }
    i -= 16384;
    if (i < 16384) { int c = i >> 7, k = i & 127; V2t[i] = f2bf(v2[k * HID + c]); return; }
    i -= 16384;
    if (i < 32768) { int c = i >> 8, k = i & 255; EW1t[i] = f2bf(ew1[k * HID + c]); return; }
    i -= 32768;
    if (i < 416 * 32) {
        int f = i >> 5, q = i & 31;
        unsigned short v = 0;
        if (f < NODE_IN) {
            if (q < 7) v = f2bf(e1w[q * NODE_IN + f]);
            else if (q == 7) v = f2bf(e1b[f]);
        }
        E1T[i] = v;
        return;
    }
}

// -------------------- x -> bf16, K-padded to 416 ---------------------------
__global__ __launch_bounds__(256) void k_castx(const float* __restrict__ x,
                                               unsigned short* __restrict__ xbf) {
    const int g = blockIdx.x * 256 + threadIdx.x;
    if (g >= N_NODES * 52) return;
    const int row = g / 52, c0 = (g - row * 52) * 8;
    s16x8 v;
#pragma unroll
    for (int j = 0; j < 8; ++j) {
        const int c = c0 + j;
        v[j] = (c < NODE_IN) ? (short)f2bf(x[row * NODE_IN + c]) : (short)0;
    }
    *(s16x8*)&xbf[row * KPAD + c0] = v;
}

// ------------------------- counting sort by dst ----------------------------
__global__ __launch_bounds__(256) void k_hist(const int* __restrict__ d32,
                                              int* __restrict__ cnt) {
    const int e = blockIdx.x * 256 + threadIdx.x;
    if (e < N_EDGES) atomicAdd(&cnt[d32[e]], 1);
}

__global__ __launch_bounds__(256) void k_scanA(const int* __restrict__ cnt,
                                               int* __restrict__ bsum) {
    __shared__ int wt[4];
    const int t = threadIdx.x;
    const int i = blockIdx.x * 256 + t;
    int v = (i < N_NODES) ? cnt[i] : 0;
#pragma unroll
    for (int off = 32; off; off >>= 1) v += __shfl_down(v, off);
    if ((t & 63) == 0) wt[t >> 6] = v;
    __syncthreads();
    if (t == 0) bsum[blockIdx.x] = wt[0] + wt[1] + wt[2] + wt[3];
}

// cnt/rowptr[i] <- exclusive prefix sum; cnt doubles as scatter cursor.
__global__ __launch_bounds__(256) void k_scanC(int* __restrict__ cnt,
                                               const int* __restrict__ bsum,
                                               int* __restrict__ rowptr) {
    __shared__ int wt[4];
    __shared__ int wt2[4];
    __shared__ int sh_bofs;
    const int t = threadIdx.x, b = blockIdx.x;
    int accp = 0;
    for (int i = t; i < NB_SCAN; i += 256) if (i < b) accp += bsum[i];
#pragma unroll
    for (int off = 32; off; off >>= 1) accp += __shfl_down(accp, off);
    if ((t & 63) == 0) wt[t >> 6] = accp;
    __syncthreads();
    if (t == 0) sh_bofs = wt[0] + wt[1] + wt[2] + wt[3];
    const int i = b * 256 + t;
    const int v = (i < N_NODES) ? cnt[i] : 0;
    int inc = v;
    const int lane = t & 63;
#pragma unroll
    for (int off = 1; off < 64; off <<= 1) {
        int u = __shfl_up(inc, off);
        if (lane >= off) inc += u;
    }
    if (lane == 63) wt2[t >> 6] = inc;
    __syncthreads();
    int wbase = 0;
    for (int wI = 0; wI < (t >> 6); ++wI) wbase += wt2[wI];
    if (i < N_NODES) {
        const int ex = sh_bofs + wbase + inc - v;
        cnt[i] = ex;
        rowptr[i] = ex;
    }
}

__global__ __launch_bounds__(256) void k_scatter(const int* __restrict__ s32,
                                                 const int* __restrict__ d32,
                                                 const float* __restrict__ ea,
                                                 int* __restrict__ cur,
                                                 int* __restrict__ ss2,
                                                 int* __restrict__ ds2,
                                                 int* __restrict__ ep,
                                                 float* __restrict__ eas) {
    const int e = blockIdx.x * 256 + threadIdx.x;
    if (e < N_EDGES) {
        const int d = d32[e];
        const int pos = atomicAdd(&cur[d], 1);
        ss2[pos] = s32[e];
        ds2[pos] = d;
        ep[pos]  = e;
#pragma unroll
        for (int q = 0; q < 7; ++q) eas[pos * 8 + q] = ea[e * 7 + q];
        eas[pos * 8 + 7] = 0.f;
    }
}

// Full B-tile staging: 128 cols x 32 k bf16 -> 256 threads x 16 shorts.
#define STAGE_B(dst, srcbase, stride_) do {                                   \
    const int col_ = t >> 1, h_ = t & 1;                                      \
    *(s16x8*)&(dst)[col_ * 40 + h_ * 16] =                                    \
        *(const s16x8*)&(srcbase)[col_ * (stride_) + h_ * 16];                \
    *(s16x8*)&(dst)[col_ * 40 + h_ * 16 + 8] =                                \
        *(const s16x8*)&(srcbase)[col_ * (stride_) + h_ * 16 + 8];            \
} while (0)

// ----------------- conv1: per-edge msg GEMM + segmented reduce -------------
// le = [ea|1]@[e1w;e1b] computed via MFMA into LDS; A-stage = relu(x+le).
__global__ __launch_bounds__(256) void k_edge1(const unsigned short* __restrict__ xbf,
                                               const int* __restrict__ ss2,
                                               const int* __restrict__ ds2,
                                               const float* __restrict__ eas,
                                               const unsigned short* __restrict__ E1T,
                                               const unsigned short* __restrict__ W1t,
                                               float* __restrict__ yagg) {
    __shared__ __align__(16) char pool[26880];
    unsigned short* Asm  = (unsigned short*)(pool);           // 5120
    unsigned short* Bsm  = (unsigned short*)(pool + 5120);    // 10240
    unsigned short* Bsm2 = (unsigned short*)(pool + 15360);   // 2560
    float* le_lds = (float*)(pool + 17920);                   // 64*33*4 = 8448
    int* ss_s     = (int*)(pool + 26368);                     // 256
    int* dst_s    = (int*)(pool + 26624);                     // 256
    float* Csm    = (float*)(pool);                           // epilogue alias 16512

    const int t = threadIdx.x;
    const int e0 = blockIdx.x * 64;

    if (t < 64) ss_s[t] = ss2[e0 + t];
    else if (t < 128) dst_s[t - 64] = ds2[e0 + (t - 64)];

    const int lane = t & 63, wid = t >> 6;
    const int wr = wid >> 1, wc = wid & 1;
    const int r = t >> 2, kc = (t & 3) * 8;
    const int rA = lane & 15;
    const int koff = (lane >> 4) * 8;

    // build eap tile [64][32]: cols 0..6 = ea, 7 = 1.0, rest 0
    {
        s16x8 v;
#pragma unroll
        for (int j = 0; j < 8; ++j) v[j] = 0;
        if (kc == 0) {
#pragma unroll
            for (int q = 0; q < 7; ++q) v[q] = (short)f2bf(eas[(e0 + r) * 8 + q]);
            v[7] = (short)0x3F80;   // 1.0 bf16
        }
        *(s16x8*)&Asm[r * 40 + kc] = v;
    }
    __syncthreads();
    const s16x8 eap0 = *(const s16x8*)&Asm[(wr * 32 + rA) * 40 + koff];
    const s16x8 eap1 = *(const s16x8*)&Asm[(wr * 32 + 16 + rA) * 40 + koff];
    __syncthreads();

    const int srow = ss_s[r];
    f32x4 acc[2][4];
    const f32x4 zero = {0.f, 0.f, 0.f, 0.f};
#pragma unroll
    for (int mi = 0; mi < 2; ++mi)
#pragma unroll
        for (int ni = 0; ni < 4; ++ni) acc[mi][ni] = zero;

    s16x8 xa_n = *(const s16x8*)&xbf[srow * KPAD + kc];
    for (int ks = 0; ks < 13; ++ks) {
        const s16x8 xa = xa_n;
        if (ks < 12) xa_n = *(const s16x8*)&xbf[srow * KPAD + (ks + 1) * 32 + kc];
        STAGE_B(Bsm, &W1t[ks * 32], KPAD);
        if (t < 128) {      // stage E1T slice [32 n][32 q]
            const int n = t >> 2, qg = (t & 3) * 8;
            *(s16x8*)&Bsm2[n * 40 + qg] = *(const s16x8*)&E1T[(ks * 32 + n) * 32 + qg];
        }
        __syncthreads();
        {   // LE MFMA: LE[64][32] = eap @ E1T_slice^T
            s16x8 b2 = *(const s16x8*)&Bsm2[(wc * 16 + rA) * 40 + koff];
            f32x4 le0 = __builtin_amdgcn_mfma_f32_16x16x32_bf16(eap0, b2, zero, 0, 0, 0);
            f32x4 le1 = __builtin_amdgcn_mfma_f32_16x16x32_bf16(eap1, b2, zero, 0, 0, 0);
            const int cw = wc * 16 + rA;
#pragma unroll
            for (int reg = 0; reg < 4; ++reg) {
                const int row = wr * 32 + (lane >> 4) * 4 + reg;
                le_lds[row * 33 + cw] = le0[reg];
                le_lds[(row + 16) * 33 + cw] = le1[reg];
            }
        }
        __syncthreads();
        {   // A stage: relu(x + le) -> bf16
            const float* lep = &le_lds[r * 33 + kc];
            s16x8 v;
#pragma unroll
            for (int j = 0; j < 8; ++j)
                v[j] = (short)f2bf(fmaxf(bf2f(xa[j]) + lep[j], 0.f));
            *(s16x8*)&Asm[r * 40 + kc] = v;
        }
        __syncthreads();
        s16x8 a0 = *(const s16x8*)&Asm[(wr * 32 + rA) * 40 + koff];
        s16x8 a1 = *(const s16x8*)&Asm[(wr * 32 + 16 + rA) * 40 + koff];
#pragma unroll
        for (int ni = 0; ni < 4; ++ni) {
            s16x8 b = *(const s16x8*)&Bsm[(wc * 64 + ni * 16 + rA) * 40 + koff];
            acc[0][ni] = __builtin_amdgcn_mfma_f32_16x16x32_bf16(a0, b, acc[0][ni], 0, 0, 0);
            acc[1][ni] = __builtin_amdgcn_mfma_f32_16x16x32_bf16(a1, b, acc[1][ni], 0, 0, 0);
        }
        __syncthreads();
    }
    // segmented-reduce epilogue: 2 passes x 32 rows; 256 threads (16-row halves)
    const int gq = lane >> 4;
    const int cb = wc * 64 + rA;
#pragma unroll
    for (int p = 0; p < 2; ++p) {
        if (wr == p) {
#pragma unroll
            for (int mi = 0; mi < 2; ++mi)
#pragma unroll
                for (int reg = 0; reg < 4; ++reg) {
                    const int row = mi * 16 + gq * 4 + reg;   // 0..31 local
#pragma unroll
                    for (int ni = 0; ni < 4; ++ni)
                        Csm[row * 129 + cb + ni * 16] = acc[mi][ni][reg];
                }
        }
        __syncthreads();
        {
            const int col = t & 127, half = t >> 7;
            const int b0 = p * 32 + half * 16;
            float s = 0.f;
            int prev = dst_s[b0];
            for (int rr = 0; rr < 16; ++rr) {
                const int d = dst_s[b0 + rr];
                const float v = Csm[(half * 16 + rr) * 129 + col];
                if (d != prev) { atomicAdd(&yagg[prev * HID + col], s); s = 0.f; prev = d; }
                s += v;
            }
            atomicAdd(&yagg[prev * HID + col], s);
        }
        __syncthreads();
    }
}

// -------------- node MLP1: r1b = bf16(relu(relu(x@W1+yagg+b1)@W2+b2)) ------
__global__ __launch_bounds__(256) void k_node1(const unsigned short* __restrict__ xbf,
                                               const float* __restrict__ yagg,
                                               const unsigned short* __restrict__ W1t,
                                               const unsigned short* __restrict__ W2t,
                                               const float* __restrict__ b1,
                                               const float* __restrict__ b2,
                                               unsigned short* __restrict__ r1b) {
    __shared__ __align__(16) unsigned short Asm[64 * 40];
    __shared__ __align__(16) unsigned short Bsm[128 * 40];
    __shared__ __align__(16) unsigned short Hsm[64 * 136];
    const int t = threadIdx.x;
    const int i0 = blockIdx.x * 64;
    const int lane = t & 63, wid = t >> 6, wr = wid >> 1, wc = wid & 1;
    const int r = t >> 2, kc = (t & 3) * 8;
    const int rg = i0 + r;
    const bool rvalid = rg < N_NODES;

    f32x4 acc[2][4];
    const f32x4 zero = {0.f, 0.f, 0.f, 0.f};
#pragma unroll
    for (int mi = 0; mi < 2; ++mi)
#pragma unroll
        for (int ni = 0; ni < 4; ++ni) acc[mi][ni] = zero;

    for (int ks = 0; ks < 13; ++ks) {
        {
            s16x8 v;
            if (rvalid) v = *(const s16x8*)&xbf[rg * KPAD + ks * 32 + kc];
            else {
#pragma unroll
                for (int j = 0; j < 8; ++j) v[j] = 0;
            }
            *(s16x8*)&Asm[r * 40 + kc] = v;
        }
        STAGE_B(Bsm, &W1t[ks * 32], KPAD);
        __syncthreads();
        const int koff = (lane >> 4) * 8;
        const int rA = lane & 15;
        s16x8 a0 = *(const s16x8*)&Asm[(wr * 32 + rA) * 40 + koff];
        s16x8 a1 = *(const s16x8*)&Asm[(wr * 32 + 16 + rA) * 40 + koff];
#pragma unroll
        for (int ni = 0; ni < 4; ++ni) {
            s16x8 b = *(const s16x8*)&Bsm[(wc * 64 + ni * 16 + rA) * 40 + koff];
            acc[0][ni] = __builtin_amdgcn_mfma_f32_16x16x32_bf16(a0, b, acc[0][ni], 0, 0, 0);
            acc[1][ni] = __builtin_amdgcn_mfma_f32_16x16x32_bf16(a1, b, acc[1][ni], 0, 0, 0);
        }
        __syncthreads();
    }
    const int jb = wc * 64 + (lane & 15);
#pragma unroll
    for (int mi = 0; mi < 2; ++mi) {
#pragma unroll
        for (int reg = 0; reg < 4; ++reg) {
            const int rloc = wr * 32 + mi * 16 + (lane >> 4) * 4 + reg;
            const int rowg = i0 + rloc;
#pragma unroll
            for (int ni = 0; ni < 4; ++ni) {
                const int j = jb + ni * 16;
                float v = acc[mi][ni][reg];
                if (rowg < N_NODES) {
                    v += yagg[rowg * HID + j] + b1[j];
                    v = fmaxf(v, 0.f);
                } else v = 0.f;
                Hsm[rloc * 136 + j] = f2bf(v);
            }
        }
    }
    __syncthreads();
    f32x4 acc2[2][4];
#pragma unroll
    for (int mi = 0; mi < 2; ++mi)
#pragma unroll
        for (int ni = 0; ni < 4; ++ni) acc2[mi][ni] = zero;

    for (int ks = 0; ks < 4; ++ks) {
        STAGE_B(Bsm, &W2t[ks * 32], HID);
        __syncthreads();
        const int koff = (lane >> 4) * 8;
        const int rA = lane & 15;
        s16x8 a0 = *(const s16x8*)&Hsm[(wr * 32 + rA) * 136 + ks * 32 + koff];
        s16x8 a1 = *(const s16x8*)&Hsm[(wr * 32 + 16 + rA) * 136 + ks * 32 + koff];
#pragma unroll
        for (int ni = 0; ni < 4; ++ni) {
            s16x8 b = *(const s16x8*)&Bsm[(wc * 64 + ni * 16 + rA) * 40 + koff];
            acc2[0][ni] = __builtin_amdgcn_mfma_f32_16x16x32_bf16(a0, b, acc2[0][ni], 0, 0, 0);
            acc2[1][ni] = __builtin_amdgcn_mfma_f32_16x16x32_bf16(a1, b, acc2[1][ni], 0, 0, 0);
        }
        __syncthreads();
    }
#pragma unroll
    for (int mi = 0; mi < 2; ++mi) {
#pragma unroll
        for (int reg = 0; reg < 4; ++reg) {
            const int rloc = wr * 32 + mi * 16 + (lane >> 4) * 4 + reg;
            const int rowg = i0 + rloc;
            if (rowg < N_NODES) {
#pragma unroll
                for (int ni = 0; ni < 4; ++ni) {
                    const int j = jb + ni * 16;
                    float v = acc2[mi][ni][reg] + b2[j];
                    r1b[rowg * HID + j] = f2bf(fmaxf(v, 0.f));
                }
            }
        }
    }
}

// ---- fused conv2: node-centric msg accumulate (no atomics) + 2-layer MLP --
__global__ __launch_bounds__(256) void k_conv2(const unsigned short* __restrict__ r1b,
                                               const int* __restrict__ ss2,
                                               const float* __restrict__ eas,
                                               const int* __restrict__ rowptr,
                                               const float* __restrict__ e2w,
                                               const float* __restrict__ e2b,
                                               const unsigned short* __restrict__ V1t,
                                               const unsigned short* __restrict__ V2t,
                                               const float* __restrict__ b1,
                                               const float* __restrict__ b2,
                                               unsigned short* __restrict__ r2) {
    __shared__ float w_s[7 * HID];
    __shared__ float eb_s[HID];
    __shared__ __align__(16) unsigned short Bsm[128 * 40];
    __shared__ __align__(16) unsigned short Hsm[64 * 136];
    const int t = threadIdx.x;
    const int i0 = blockIdx.x * 64;
    for (int i = t; i < 7 * HID; i += 256) w_s[i] = e2w[i];
    if (t < HID) eb_s[t] = e2b[t];
    __syncthreads();

    const int r = t >> 2, c0 = (t & 3) * 32;
    const int g = i0 + r;
    float acc32[32];
#pragma unroll
    for (int j = 0; j < 32; ++j) acc32[j] = 0.f;

    if (g < N_NODES) {
        const int eB = rowptr[g];
        const int eE = (g + 1 < N_NODES) ? rowptr[g + 1] : N_EDGES;
        for (int e = eB; e < eE; ++e) {
            float eav[7];
#pragma unroll
            for (int q = 0; q < 7; ++q) eav[q] = eas[e * 8 + q];
            const int src = ss2[e];
            const s16x8* rp = (const s16x8*)&r1b[src * HID + c0];
#pragma unroll
            for (int u = 0; u < 4; ++u) {
                s16x8 hv = rp[u];
                float vv[8];
#pragma unroll
                for (int j = 0; j < 8; ++j) vv[j] = bf2f(hv[j]) + eb_s[c0 + u * 8 + j];
#pragma unroll
                for (int q = 0; q < 7; ++q) {
                    const f32x4 w0 = *(const f32x4*)&w_s[q * HID + c0 + u * 8];
                    const f32x4 w1 = *(const f32x4*)&w_s[q * HID + c0 + u * 8 + 4];
#pragma unroll
                    for (int j = 0; j < 4; ++j) {
                        vv[j]     = fmaf(eav[q], w0[j], vv[j]);
                        vv[4 + j] = fmaf(eav[q], w1[j], vv[4 + j]);
                    }
                }
#pragma unroll
                for (int j = 0; j < 8; ++j) acc32[u * 8 + j] += fmaxf(vv[j], 0.f);
            }
        }
    }
    // h = r1 + agg -> bf16 -> Hsm
    {
        if (g < N_NODES) {
            const s16x8* rp = (const s16x8*)&r1b[g * HID + c0];
#pragma unroll
            for (int u = 0; u < 4; ++u) {
                s16x8 hv = rp[u];
                s16x8 o;
#pragma unroll
                for (int j = 0; j < 8; ++j)
                    o[j] = (short)f2bf(bf2f(hv[j]) + acc32[u * 8 + j]);
                *(s16x8*)&Hsm[r * 136 + c0 + u * 8] = o;
            }
        } else {
            s16x8 o;
#pragma unroll
            for (int j = 0; j < 8; ++j) o[j] = 0;
#pragma unroll
            for (int u = 0; u < 4; ++u)
                *(s16x8*)&Hsm[r * 136 + c0 + u * 8] = o;
        }
    }
    __syncthreads();

    const int lane = t & 63, wid = t >> 6, wr = wid >> 1, wc = wid & 1;
    const int rA = lane & 15, koff = (lane >> 4) * 8;
    const f32x4 zero = {0.f, 0.f, 0.f, 0.f};
    f32x4 acc[2][4];
#pragma unroll
    for (int mi = 0; mi < 2; ++mi)
#pragma unroll
        for (int ni = 0; ni < 4; ++ni) acc[mi][ni] = zero;

    for (int ks = 0; ks < 4; ++ks) {
        STAGE_B(Bsm, &V1t[ks * 32], HID);
        __syncthreads();
        s16x8 a0 = *(const s16x8*)&Hsm[(wr * 32 + rA) * 136 + ks * 32 + koff];
        s16x8 a1 = *(const s16x8*)&Hsm[(wr * 32 + 16 + rA) * 136 + ks * 32 + koff];
#pragma unroll
        for (int ni = 0; ni < 4; ++ni) {
            s16x8 b = *(const s16x8*)&Bsm[(wc * 64 + ni * 16 + rA) * 40 + koff];
            acc[0][ni] = __builtin_amdgcn_mfma_f32_16x16x32_bf16(a0, b, acc[0][ni], 0, 0, 0);
            acc[1][ni] = __builtin_amdgcn_mfma_f32_16x16x32_bf16(a1, b, acc[1][ni], 0, 0, 0);
        }
        __syncthreads();
    }
    const int jb = wc * 64 + rA;
#pragma unroll
    for (int mi = 0; mi < 2; ++mi) {
#pragma unroll
        for (int reg = 0; reg < 4; ++reg) {
            const int rloc = wr * 32 + mi * 16 + (lane >> 4) * 4 + reg;
#pragma unroll
            for (int ni = 0; ni < 4; ++ni) {
                const int j = jb + ni * 16;
                float v = acc[mi][ni][reg] + b1[j];
                Hsm[rloc * 136 + j] = f2bf(fmaxf(v, 0.f));
            }
        }
    }
    __syncthreads();
    f32x4 acc2[2][4];
#pragma unroll
    for (int mi = 0; mi < 2; ++mi)
#pragma unroll
        for (int ni = 0; ni < 4; ++ni) acc2[mi][ni] = zero;

    for (int ks = 0; ks < 4; ++ks) {
        STAGE_B(Bsm, &V2t[ks * 32], HID);
        __syncthreads();
        s16x8 a0 = *(const s16x8*)&Hsm[(wr * 32 + rA) * 136 + ks * 32 + koff];
        s16x8 a1 = *(const s16x8*)&Hsm[(wr * 32 + 16 + rA) * 136 + ks * 32 + koff];
#pragma unroll
        for (int ni = 0; ni < 4; ++ni) {
            s16x8 b = *(const s16x8*)&Bsm[(wc * 64 + ni * 16 + rA) * 40 + koff];
            acc2[0][ni] = __builtin_amdgcn_mfma_f32_16x16x32_bf16(a0, b, acc2[0][ni], 0, 0, 0);
            acc2[1][ni] = __builtin_amdgcn_mfma_f32_16x16x32_bf16(a1, b, acc2[1][ni], 0, 0, 0);
        }
        __syncthreads();
    }
#pragma unroll
    for (int mi = 0; mi < 2; ++mi) {
#pragma unroll
        for (int reg = 0; reg < 4; ++reg) {
            const int rloc = wr * 32 + mi * 16 + (lane >> 4) * 4 + reg;
            const int rowg = i0 + rloc;
            if (rowg < N_NODES) {
#pragma unroll
                for (int ni = 0; ni < 4; ++ni) {
                    const int j = jb + ni * 16;
                    float v = acc2[mi][ni][reg] + b2[j];
                    r2[rowg * HID + j] = f2bf(fmaxf(v, 0.f));
                }
            }
        }
    }
}

// ------- edge head (dst-sorted): out[ep] = relu([r2_s|r2_d|ea]@W1+b1)@W2+b2 -
__global__ __launch_bounds__(256) void k_head(const unsigned short* __restrict__ r2,
                                              const int* __restrict__ ss2,
                                              const int* __restrict__ ds2,
                                              const int* __restrict__ ep,
                                              const float* __restrict__ eas,
                                              const unsigned short* __restrict__ EW1t,
                                              const float* __restrict__ emw1,
                                              const float* __restrict__ emb1,
                                              const float* __restrict__ emw2,
                                              const float* __restrict__ emb2,
                                              float* __restrict__ out) {
    __shared__ __align__(16) unsigned short Asm[64 * 40];
    __shared__ __align__(16) unsigned short Bsm[128 * 40];
    __shared__ float Hsm[64 * 129];
    __shared__ float ew_ea[7 * HID];
    __shared__ float eb1_s[HID];
    __shared__ float w2_s[256];
    __shared__ float b2_s[2];
    __shared__ float ea_s[64 * 8];
    __shared__ int src_s[64];
    __shared__ int dst_s[64];
    __shared__ int ep_s[64];
    __shared__ float red[512];
    const int t = threadIdx.x;
    const int e0 = blockIdx.x * 64;

    for (int i = t; i < 7 * HID; i += 256) ew_ea[i] = emw1[256 * HID + i];
    if (t < HID) eb1_s[t] = emb1[t];
    if (t < 256) w2_s[t] = emw2[t];
    if (t < 2) b2_s[t] = emb2[t];
    for (int i = t; i < 512; i += 256) ea_s[i] = eas[e0 * 8 + i];
    if (t < 64) src_s[t] = ss2[e0 + t];
    else if (t < 128) dst_s[t - 64] = ds2[e0 + (t - 64)];
    else if (t < 192) ep_s[t - 128] = ep[e0 + (t - 128)];
    __syncthreads();

    const int lane = t & 63, wid = t >> 6, wr = wid >> 1, wc = wid & 1;
    const int r = t >> 2, kc = (t & 3) * 8;

    f32x4 acc[2][4];
    const f32x4 zero = {0.f, 0.f, 0.f, 0.f};
#pragma unroll
    for (int mi = 0; mi < 2; ++mi)
#pragma unroll
        for (int ni = 0; ni < 4; ++ni) acc[mi][ni] = zero;

    for (int ks = 0; ks < 8; ++ks) {
        {
            const int k = ks * 32 + kc;
            const unsigned short* p = (k < HID) ? &r2[src_s[r] * HID + k]
                                                : &r2[dst_s[r] * HID + (k - HID)];
            *(s16x8*)&Asm[r * 40 + kc] = *(const s16x8*)p;
        }
        STAGE_B(Bsm, &EW1t[ks * 32], 256);
        __syncthreads();
        const int koff = (lane >> 4) * 8;
        const int rA = lane & 15;
        s16x8 a0 = *(const s16x8*)&Asm[(wr * 32 + rA) * 40 + koff];
        s16x8 a1 = *(const s16x8*)&Asm[(wr * 32 + 16 + rA) * 40 + koff];
#pragma unroll
        for (int ni = 0; ni < 4; ++ni) {
            s16x8 b = *(const s16x8*)&Bsm[(wc * 64 + ni * 16 + rA) * 40 + koff];
            acc[0][ni] = __builtin_amdgcn_mfma_f32_16x16x32_bf16(a0, b, acc[0][ni], 0, 0, 0);
            acc[1][ni] = __builtin_amdgcn_mfma_f32_16x16x32_bf16(a1, b, acc[1][ni], 0, 0, 0);
        }
        __syncthreads();
    }
    const int jb = wc * 64 + (lane & 15);
#pragma unroll
    for (int mi = 0; mi < 2; ++mi) {
#pragma unroll
        for (int reg = 0; reg < 4; ++reg) {
            const int rloc = wr * 32 + mi * 16 + (lane >> 4) * 4 + reg;
#pragma unroll
            for (int ni = 0; ni < 4; ++ni) {
                const int j = jb + ni * 16;
                float v = acc[mi][ni][reg] + eb1_s[j];
#pragma unroll
                for (int q = 0; q < 7; ++q)
                    v = fmaf(ea_s[rloc * 8 + q], ew_ea[q * HID + j], v);
                Hsm[rloc * 129 + j] = fmaxf(v, 0.f);
            }
        }
    }
    __syncthreads();
    {
        const int e = t & 63, p = t >> 6;
        const float* hb = &Hsm[e * 129 + p * 32];
        float s0 = 0.f, s1 = 0.f;
#pragma unroll
        for (int j = 0; j < 32; ++j) {
            const float h = hb[j];
            s0 = fmaf(h, w2_s[(p * 32 + j) * 2], s0);
            s1 = fmaf(h, w2_s[(p * 32 + j) * 2 + 1], s1);
        }
        red[(e * 4 + p) * 2] = s0;
        red[(e * 4 + p) * 2 + 1] = s1;
    }
    __syncthreads();
    if (t < 64) {
        float o0 = b2_s[0], o1 = b2_s[1];
#pragma unroll
        for (int p = 0; p < 4; ++p) {
            o0 += red[(t * 4 + p) * 2];
            o1 += red[(t * 4 + p) * 2 + 1];
        }
        const int oe = ep_s[t];
        out[oe * 2] = o0;
        out[oe * 2 + 1] = o1;
    }
}

// ---------------------------------------------------------------------------
extern "C" void kernel_launch(void* const* d_in, const int* in_sizes, int n_in,
                              void* d_out, int out_size, void* d_ws, size_t ws_size,
                              hipStream_t stream) {
    (void)in_sizes; (void)n_in; (void)out_size; (void)ws_size;
    const float* x    = (const float*)d_in[0];
    const unsigned* eidx = (const unsigned*)d_in[1];
    const float* ea   = (const float*)d_in[2];
    const float* e1w  = (const float*)d_in[3];
    const float* e1b  = (const float*)d_in[4];
    const float* m1w1 = (const float*)d_in[5];
    const float* m1b1 = (const float*)d_in[6];
    const float* m1w2 = (const float*)d_in[7];
    const float* m1b2 = (const float*)d_in[8];
    const float* e2w  = (const float*)d_in[9];
    const float* e2b  = (const float*)d_in[10];
    const float* m2w1 = (const float*)d_in[11];
    const float* m2b1 = (const float*)d_in[12];
    const float* m2w2 = (const float*)d_in[13];
    const float* m2b2 = (const float*)d_in[14];
    const float* emw1 = (const float*)d_in[15];
    const float* emb1 = (const float*)d_in[16];
    const float* emw2 = (const float*)d_in[17];
    const float* emb2 = (const float*)d_in[18];
    float* out = (float*)d_out;

    char* ws = (char*)d_ws;
    float* yagg = (float*)(ws + 0);                            // 51.2 MB (conv1 agg)
    unsigned short* r2 = (unsigned short*)(ws + 0);            // aliases yagg (dead after k_node1)
    unsigned short* r1b = (unsigned short*)(ws + 51200000);    // 25.6 MB
    float* eas          = (float*)(ws + 76800000);             // 19.2 MB
    unsigned short* xbf = (unsigned short*)(ws + 96000000);    // 83.2 MB -> 179,200,000
    unsigned short* W1t  = (unsigned short*)(ws + 179200000);  // 106,496
    unsigned short* W2t  = (unsigned short*)(ws + 179306496);  // 32,768
    unsigned short* V1t  = (unsigned short*)(ws + 179339264);  // 32,768
    unsigned short* V2t  = (unsigned short*)(ws + 179372032);  // 32,768
    unsigned short* EW1t = (unsigned short*)(ws + 179404800);  // 65,536
    unsigned short* E1T  = (unsigned short*)(ws + 179470336);  // 26,624 -> 179,496,960
    int* s32    = (int*)(ws + 179496960);                      // 2.4 MB
    int* d32    = (int*)(ws + 181896960);                      // 2.4 MB
    int* ss2    = (int*)(ws + 184296960);                      // 2.4 MB
    int* ds2    = (int*)(ws + 186696960);                      // 2.4 MB
    int* ep     = (int*)(ws + 189096960);                      // 2.4 MB
    int* cnt    = (int*)(ws + 191496960);                      // 400 KB
    int* rowptr = (int*)(ws + 191896960);                      // 400 KB
    int* bsum   = (int*)(ws + 192296960);                      // 4 KB

    hipMemsetAsync(yagg, 0, (size_t)N_NODES * HID * 4, stream);
    hipMemsetAsync(cnt, 0, (size_t)N_NODES * 4, stream);
    k_decode<<<2344, 256, 0, stream>>>(eidx, s32, d32);
    k_prep<<<580, 256, 0, stream>>>(m1w1, m1w2, m2w1, m2w2, emw1, e1w, e1b,
                                    W1t, W2t, V1t, V2t, EW1t, E1T);
    k_castx<<<(N_NODES * 52 + 255) / 256, 256, 0, stream>>>(x, xbf);
    k_hist<<<2344, 256, 0, stream>>>(d32, cnt);
    k_scanA<<<NB_SCAN, 256, 0, stream>>>(cnt, bsum);
    k_scanC<<<NB_SCAN, 256, 0, stream>>>(cnt, bsum, rowptr);
    k_scatter<<<2344, 256, 0, stream>>>(s32, d32, ea, cnt, ss2, ds2, ep, eas);
    k_edge1<<<N_EDGES / 64, 256, 0, stream>>>(xbf, ss2, ds2, eas, E1T, W1t, yagg);
    k_node1<<<(N_NODES + 63) / 64, 256, 0, stream>>>(xbf, yagg, W1t, W2t, m1b1, m1b2, r1b);
    k_conv2<<<(N_NODES + 63) / 64, 256, 0, stream>>>(r1b, ss2, eas, rowptr, e2w, e2b,
                                                     V1t, V2t, m2b1, m2b2, r2);
    k_head<<<N_EDGES / 64, 256, 0, stream>>>(r2, ss2, ds2, ep, eas, EW1t,
                                             emw1, emb1, emw2, emb2, out);
}

// Round 8
// 924.631 us; speedup vs baseline: 1.1674x; 1.1674x over previous
//
#include <hip/hip_runtime.h>

// ---------------------------------------------------------------------------
// GINE edge model. Round 8: keep r7's LE-MFMA k_edge1 (proven -50us);
// revert k_head to original edge order (coalesced out) and conv2 to
// edge2+node2 (r6, proven); NEW: k_head ea-part folded into MFMA acc-init
// via EWeaT (kills the 7-FMA/LDS epilogue).
// ---------------------------------------------------------------------------

using f32x4 = __attribute__((ext_vector_type(4))) float;
using s16x8 = __attribute__((ext_vector_type(8))) short;

#define N_NODES 100000
#define N_EDGES 600000
#define NODE_IN 387
#define KPAD    416   // 13 * 32
#define HID     128
#define NB_SCAN 391   // ceil(100000/256)

__device__ __forceinline__ unsigned short f2bf(float f) {
    unsigned u = __float_as_uint(f);
    u += 0x7FFFu + ((u >> 16) & 1u);   // RNE
    return (unsigned short)(u >> 16);
}
__device__ __forceinline__ float bf2f(short h) {
    return __uint_as_float(((unsigned)(unsigned short)h) << 16);
}

// --------------------------- edge_index decode -----------------------------
__global__ __launch_bounds__(256) void k_decode(const unsigned* __restrict__ w,
                                                int* __restrict__ s32,
                                                int* __restrict__ d32) {
    __shared__ unsigned long long bs[4];
    __shared__ int is64_s;
    const int t = threadIdx.x;
    unsigned any = 0;
    for (int i = 1 + 2 * t; i < 2048; i += 512) any |= w[i];
    unsigned long long b = __ballot(any != 0);
    if ((t & 63) == 0) bs[t >> 6] = b;
    __syncthreads();
    if (t == 0) is64_s = ((bs[0] | bs[1] | bs[2] | bs[3]) == 0ULL) ? 1 : 0;
    __syncthreads();
    const int is64 = is64_s;
    const int e = blockIdx.x * 256 + t;
    if (e < N_EDGES) {
        if (is64) {
            s32[e] = (int)w[2 * e];
            d32[e] = (int)w[2 * N_EDGES + 2 * e];
        } else {
            s32[e] = (int)w[e];
            d32[e] = (int)w[N_EDGES + e];
        }
    }
}

// ------------------------ weight transpose + bf16 --------------------------
// E1T[416][32]: [e1w;e1b] transposed; EWeaT[128][32]: ea-rows of em_w1 + emb1.
__global__ __launch_bounds__(256) void k_prep(const float* __restrict__ w1,
                                              const float* __restrict__ w2,
                                              const float* __restrict__ v1,
                                              const float* __restrict__ v2,
                                              const float* __restrict__ ew1,
                                              const float* __restrict__ e1w,
                                              const float* __restrict__ e1b,
                                              const float* __restrict__ emb1,
                                              unsigned short* __restrict__ W1t,
                                              unsigned short* __restrict__ W2t,
                                              unsigned short* __restrict__ V1t,
                                              unsigned short* __restrict__ V2t,
                                              unsigned short* __restrict__ EW1t,
                                              unsigned short* __restrict__ E1T,
                                              unsigned short* __restrict__ EWeaT) {
    int i = blockIdx.x * 256 + threadIdx.x;
    if (i < 128 * KPAD) {
        int c = i / KPAD, k = i - c * KPAD;
        W1t[i] = (k < NODE_IN) ? f2bf(w1[k * HID + c]) : (unsigned short)0;
        return;
    }
    i -= 128 * KPAD;
    if (i < 16384) { int c = i >> 7, k = i & 127; W2t[i] = f2bf(w2[k * HID + c]); return; }
    i -= 16384;
    if (i < 16384) { int c = i >> 7, k = i & 127; V1t[i] = f2bf(v1[k * HID + c]); return; }
    i -= 16384;
    if (i < 16384) { int c = i >> 7, k = i & 127; V2t[i] = f2bf(v2[k * HID + c]); return; }
    i -= 16384;
    if (i < 32768) { int c = i >> 8, k = i & 255; EW1t[i] = f2bf(ew1[k * HID + c]); return; }
    i -= 32768;
    if (i < 416 * 32) {
        int f = i >> 5, q = i & 31;
        unsigned short v = 0;
        if (f < NODE_IN) {
            if (q < 7) v = f2bf(e1w[q * NODE_IN + f]);
            else if (q == 7) v = f2bf(e1b[f]);
        }
        E1T[i] = v;
        return;
    }
    i -= 416 * 32;
    if (i < 128 * 32) {
        int c = i >> 5, q = i & 31;
        unsigned short v = 0;
        if (q < 7) v = f2bf(ew1[(256 + q) * HID + c]);
        else if (q == 7) v = f2bf(emb1[c]);
        EWeaT[i] = v;
        return;
    }
}

// -------------------- x -> bf16, K-padded to 416 ---------------------------
__global__ __launch_bounds__(256) void k_castx(const float* __restrict__ x,
                                               unsigned short* __restrict__ xbf) {
    const int g = blockIdx.x * 256 + threadIdx.x;
    if (g >= N_NODES * 52) return;
    const int row = g / 52, c0 = (g - row * 52) * 8;
    s16x8 v;
#pragma unroll
    for (int j = 0; j < 8; ++j) {
        const int c = c0 + j;
        v[j] = (c < NODE_IN) ? (short)f2bf(x[row * NODE_IN + c]) : (short)0;
    }
    *(s16x8*)&xbf[row * KPAD + c0] = v;
}

// ------------------------- counting sort by dst ----------------------------
__global__ __launch_bounds__(256) void k_hist(const int* __restrict__ d32,
                                              int* __restrict__ cnt) {
    const int e = blockIdx.x * 256 + threadIdx.x;
    if (e < N_EDGES) atomicAdd(&cnt[d32[e]], 1);
}

__global__ __launch_bounds__(256) void k_scanA(const int* __restrict__ cnt,
                                               int* __restrict__ bsum) {
    __shared__ int wt[4];
    const int t = threadIdx.x;
    const int i = blockIdx.x * 256 + t;
    int v = (i < N_NODES) ? cnt[i] : 0;
#pragma unroll
    for (int off = 32; off; off >>= 1) v += __shfl_down(v, off);
    if ((t & 63) == 0) wt[t >> 6] = v;
    __syncthreads();
    if (t == 0) bsum[blockIdx.x] = wt[0] + wt[1] + wt[2] + wt[3];
}

__global__ __launch_bounds__(256) void k_scanC(int* __restrict__ cnt,
                                               const int* __restrict__ bsum) {
    __shared__ int wt[4];
    __shared__ int wt2[4];
    __shared__ int sh_bofs;
    const int t = threadIdx.x, b = blockIdx.x;
    int accp = 0;
    for (int i = t; i < NB_SCAN; i += 256) if (i < b) accp += bsum[i];
#pragma unroll
    for (int off = 32; off; off >>= 1) accp += __shfl_down(accp, off);
    if ((t & 63) == 0) wt[t >> 6] = accp;
    __syncthreads();
    if (t == 0) sh_bofs = wt[0] + wt[1] + wt[2] + wt[3];
    const int i = b * 256 + t;
    const int v = (i < N_NODES) ? cnt[i] : 0;
    int inc = v;
    const int lane = t & 63;
#pragma unroll
    for (int off = 1; off < 64; off <<= 1) {
        int u = __shfl_up(inc, off);
        if (lane >= off) inc += u;
    }
    if (lane == 63) wt2[t >> 6] = inc;
    __syncthreads();
    int wbase = 0;
    for (int wI = 0; wI < (t >> 6); ++wI) wbase += wt2[wI];
    if (i < N_NODES) cnt[i] = sh_bofs + wbase + inc - v;
}

__global__ __launch_bounds__(256) void k_scatter(const int* __restrict__ s32,
                                                 const int* __restrict__ d32,
                                                 const float* __restrict__ ea,
                                                 int* __restrict__ cur,
                                                 int* __restrict__ ss2,
                                                 int* __restrict__ ds2,
                                                 float* __restrict__ eas) {
    const int e = blockIdx.x * 256 + threadIdx.x;
    if (e < N_EDGES) {
        const int d = d32[e];
        const int pos = atomicAdd(&cur[d], 1);
        ss2[pos] = s32[e];
        ds2[pos] = d;
#pragma unroll
        for (int q = 0; q < 7; ++q) eas[pos * 8 + q] = ea[e * 7 + q];
        eas[pos * 8 + 7] = 0.f;
    }
}

// Full B-tile staging: 128 cols x 32 k bf16 -> 256 threads x 16 shorts.
#define STAGE_B(dst, srcbase, stride_) do {                                   \
    const int col_ = t >> 1, h_ = t & 1;                                      \
    *(s16x8*)&(dst)[col_ * 40 + h_ * 16] =                                    \
        *(const s16x8*)&(srcbase)[col_ * (stride_) + h_ * 16];                \
    *(s16x8*)&(dst)[col_ * 40 + h_ * 16 + 8] =                                \
        *(const s16x8*)&(srcbase)[col_ * (stride_) + h_ * 16 + 8];            \
} while (0)

// ----------------- conv1: per-edge msg GEMM + segmented reduce -------------
// le = [ea|1]@[e1w;e1b] computed via MFMA into LDS; A-stage = relu(x+le).
__global__ __launch_bounds__(256) void k_edge1(const unsigned short* __restrict__ xbf,
                                               const int* __restrict__ ss2,
                                               const int* __restrict__ ds2,
                                               const float* __restrict__ eas,
                                               const unsigned short* __restrict__ E1T,
                                               const unsigned short* __restrict__ W1t,
                                               float* __restrict__ yagg) {
    __shared__ __align__(16) char pool[26880];
    unsigned short* Asm  = (unsigned short*)(pool);           // 5120
    unsigned short* Bsm  = (unsigned short*)(pool + 5120);    // 10240
    unsigned short* Bsm2 = (unsigned short*)(pool + 15360);   // 2560
    float* le_lds = (float*)(pool + 17920);                   // 64*33*4 = 8448
    int* ss_s     = (int*)(pool + 26368);                     // 256
    int* dst_s    = (int*)(pool + 26624);                     // 256
    float* Csm    = (float*)(pool);                           // epilogue alias 16512

    const int t = threadIdx.x;
    const int e0 = blockIdx.x * 64;

    if (t < 64) ss_s[t] = ss2[e0 + t];
    else if (t < 128) dst_s[t - 64] = ds2[e0 + (t - 64)];

    const int lane = t & 63, wid = t >> 6;
    const int wr = wid >> 1, wc = wid & 1;
    const int r = t >> 2, kc = (t & 3) * 8;
    const int rA = lane & 15;
    const int koff = (lane >> 4) * 8;

    // build eap tile [64][32]: cols 0..6 = ea, 7 = 1.0, rest 0
    {
        s16x8 v;
#pragma unroll
        for (int j = 0; j < 8; ++j) v[j] = 0;
        if (kc == 0) {
#pragma unroll
            for (int q = 0; q < 7; ++q) v[q] = (short)f2bf(eas[(e0 + r) * 8 + q]);
            v[7] = (short)0x3F80;   // 1.0 bf16
        }
        *(s16x8*)&Asm[r * 40 + kc] = v;
    }
    __syncthreads();
    const s16x8 eap0 = *(const s16x8*)&Asm[(wr * 32 + rA) * 40 + koff];
    const s16x8 eap1 = *(const s16x8*)&Asm[(wr * 32 + 16 + rA) * 40 + koff];
    __syncthreads();

    const int srow = ss_s[r];
    f32x4 acc[2][4];
    const f32x4 zero = {0.f, 0.f, 0.f, 0.f};
#pragma unroll
    for (int mi = 0; mi < 2; ++mi)
#pragma unroll
        for (int ni = 0; ni < 4; ++ni) acc[mi][ni] = zero;

    s16x8 xa_n = *(const s16x8*)&xbf[srow * KPAD + kc];
    for (int ks = 0; ks < 13; ++ks) {
        const s16x8 xa = xa_n;
        if (ks < 12) xa_n = *(const s16x8*)&xbf[srow * KPAD + (ks + 1) * 32 + kc];
        STAGE_B(Bsm, &W1t[ks * 32], KPAD);
        if (t < 128) {      // stage E1T slice [32 n][32 q]
            const int n = t >> 2, qg = (t & 3) * 8;
            *(s16x8*)&Bsm2[n * 40 + qg] = *(const s16x8*)&E1T[(ks * 32 + n) * 32 + qg];
        }
        __syncthreads();
        {   // LE MFMA: LE[64][32] = eap @ E1T_slice^T
            s16x8 b2 = *(const s16x8*)&Bsm2[(wc * 16 + rA) * 40 + koff];
            f32x4 le0 = __builtin_amdgcn_mfma_f32_16x16x32_bf16(eap0, b2, zero, 0, 0, 0);
            f32x4 le1 = __builtin_amdgcn_mfma_f32_16x16x32_bf16(eap1, b2, zero, 0, 0, 0);
            const int cw = wc * 16 + rA;
#pragma unroll
            for (int reg = 0; reg < 4; ++reg) {
                const int row = wr * 32 + (lane >> 4) * 4 + reg;
                le_lds[row * 33 + cw] = le0[reg];
                le_lds[(row + 16) * 33 + cw] = le1[reg];
            }
        }
        __syncthreads();
        {   // A stage: relu(x + le) -> bf16
            const float* lep = &le_lds[r * 33 + kc];
            s16x8 v;
#pragma unroll
            for (int j = 0; j < 8; ++j)
                v[j] = (short)f2bf(fmaxf(bf2f(xa[j]) + lep[j], 0.f));
            *(s16x8*)&Asm[r * 40 + kc] = v;
        }
        __syncthreads();
        s16x8 a0 = *(const s16x8*)&Asm[(wr * 32 + rA) * 40 + koff];
        s16x8 a1 = *(const s16x8*)&Asm[(wr * 32 + 16 + rA) * 40 + koff];
#pragma unroll
        for (int ni = 0; ni < 4; ++ni) {
            s16x8 b = *(const s16x8*)&Bsm[(wc * 64 + ni * 16 + rA) * 40 + koff];
            acc[0][ni] = __builtin_amdgcn_mfma_f32_16x16x32_bf16(a0, b, acc[0][ni], 0, 0, 0);
            acc[1][ni] = __builtin_amdgcn_mfma_f32_16x16x32_bf16(a1, b, acc[1][ni], 0, 0, 0);
        }
        __syncthreads();
    }
    // segmented-reduce epilogue: 2 passes x 32 rows; 256 threads (16-row halves)
    const int gq = lane >> 4;
    const int cb = wc * 64 + rA;
#pragma unroll
    for (int p = 0; p < 2; ++p) {
        if (wr == p) {
#pragma unroll
            for (int mi = 0; mi < 2; ++mi)
#pragma unroll
                for (int reg = 0; reg < 4; ++reg) {
                    const int row = mi * 16 + gq * 4 + reg;   // 0..31 local
#pragma unroll
                    for (int ni = 0; ni < 4; ++ni)
                        Csm[row * 129 + cb + ni * 16] = acc[mi][ni][reg];
                }
        }
        __syncthreads();
        {
            const int col = t & 127, half = t >> 7;
            const int b0 = p * 32 + half * 16;
            float s = 0.f;
            int prev = dst_s[b0];
            for (int rr = 0; rr < 16; ++rr) {
                const int d = dst_s[b0 + rr];
                const float v = Csm[(half * 16 + rr) * 129 + col];
                if (d != prev) { atomicAdd(&yagg[prev * HID + col], s); s = 0.f; prev = d; }
                s += v;
            }
            atomicAdd(&yagg[prev * HID + col], s);
        }
        __syncthreads();
    }
}

// -------------- node MLP1: r1b = bf16(relu(relu(x@W1+yagg+b1)@W2+b2)) ------
__global__ __launch_bounds__(256) void k_node1(const unsigned short* __restrict__ xbf,
                                               const float* __restrict__ yagg,
                                               const unsigned short* __restrict__ W1t,
                                               const unsigned short* __restrict__ W2t,
                                               const float* __restrict__ b1,
                                               const float* __restrict__ b2,
                                               unsigned short* __restrict__ r1b) {
    __shared__ __align__(16) unsigned short Asm[64 * 40];
    __shared__ __align__(16) unsigned short Bsm[128 * 40];
    __shared__ __align__(16) unsigned short Hsm[64 * 136];
    const int t = threadIdx.x;
    const int i0 = blockIdx.x * 64;
    const int lane = t & 63, wid = t >> 6, wr = wid >> 1, wc = wid & 1;
    const int r = t >> 2, kc = (t & 3) * 8;
    const int rg = i0 + r;
    const bool rvalid = rg < N_NODES;

    f32x4 acc[2][4];
    const f32x4 zero = {0.f, 0.f, 0.f, 0.f};
#pragma unroll
    for (int mi = 0; mi < 2; ++mi)
#pragma unroll
        for (int ni = 0; ni < 4; ++ni) acc[mi][ni] = zero;

    for (int ks = 0; ks < 13; ++ks) {
        {
            s16x8 v;
            if (rvalid) v = *(const s16x8*)&xbf[rg * KPAD + ks * 32 + kc];
            else {
#pragma unroll
                for (int j = 0; j < 8; ++j) v[j] = 0;
            }
            *(s16x8*)&Asm[r * 40 + kc] = v;
        }
        STAGE_B(Bsm, &W1t[ks * 32], KPAD);
        __syncthreads();
        const int koff = (lane >> 4) * 8;
        const int rA = lane & 15;
        s16x8 a0 = *(const s16x8*)&Asm[(wr * 32 + rA) * 40 + koff];
        s16x8 a1 = *(const s16x8*)&Asm[(wr * 32 + 16 + rA) * 40 + koff];
#pragma unroll
        for (int ni = 0; ni < 4; ++ni) {
            s16x8 b = *(const s16x8*)&Bsm[(wc * 64 + ni * 16 + rA) * 40 + koff];
            acc[0][ni] = __builtin_amdgcn_mfma_f32_16x16x32_bf16(a0, b, acc[0][ni], 0, 0, 0);
            acc[1][ni] = __builtin_amdgcn_mfma_f32_16x16x32_bf16(a1, b, acc[1][ni], 0, 0, 0);
        }
        __syncthreads();
    }
    const int jb = wc * 64 + (lane & 15);
#pragma unroll
    for (int mi = 0; mi < 2; ++mi) {
#pragma unroll
        for (int reg = 0; reg < 4; ++reg) {
            const int rloc = wr * 32 + mi * 16 + (lane >> 4) * 4 + reg;
            const int rowg = i0 + rloc;
#pragma unroll
            for (int ni = 0; ni < 4; ++ni) {
                const int j = jb + ni * 16;
                float v = acc[mi][ni][reg];
                if (rowg < N_NODES) {
                    v += yagg[rowg * HID + j] + b1[j];
                    v = fmaxf(v, 0.f);
                } else v = 0.f;
                Hsm[rloc * 136 + j] = f2bf(v);
            }
        }
    }
    __syncthreads();
    f32x4 acc2[2][4];
#pragma unroll
    for (int mi = 0; mi < 2; ++mi)
#pragma unroll
        for (int ni = 0; ni < 4; ++ni) acc2[mi][ni] = zero;

    for (int ks = 0; ks < 4; ++ks) {
        STAGE_B(Bsm, &W2t[ks * 32], HID);
        __syncthreads();
        const int koff = (lane >> 4) * 8;
        const int rA = lane & 15;
        s16x8 a0 = *(const s16x8*)&Hsm[(wr * 32 + rA) * 136 + ks * 32 + koff];
        s16x8 a1 = *(const s16x8*)&Hsm[(wr * 32 + 16 + rA) * 136 + ks * 32 + koff];
#pragma unroll
        for (int ni = 0; ni < 4; ++ni) {
            s16x8 b = *(const s16x8*)&Bsm[(wc * 64 + ni * 16 + rA) * 40 + koff];
            acc2[0][ni] = __builtin_amdgcn_mfma_f32_16x16x32_bf16(a0, b, acc2[0][ni], 0, 0, 0);
            acc2[1][ni] = __builtin_amdgcn_mfma_f32_16x16x32_bf16(a1, b, acc2[1][ni], 0, 0, 0);
        }
        __syncthreads();
    }
#pragma unroll
    for (int mi = 0; mi < 2; ++mi) {
#pragma unroll
        for (int reg = 0; reg < 4; ++reg) {
            const int rloc = wr * 32 + mi * 16 + (lane >> 4) * 4 + reg;
            const int rowg = i0 + rloc;
            if (rowg < N_NODES) {
#pragma unroll
                for (int ni = 0; ni < 4; ++ni) {
                    const int j = jb + ni * 16;
                    float v = acc2[mi][ni][reg] + b2[j];
                    r1b[rowg * HID + j] = f2bf(fmaxf(v, 0.f));
                }
            }
        }
    }
}

// ---- conv2 message pass (sorted, bf16 gather) -----------------------------
__global__ __launch_bounds__(256) void k_edge2(const unsigned short* __restrict__ r1b,
                                               const int* __restrict__ ss2,
                                               const int* __restrict__ ds2,
                                               const float* __restrict__ eas,
                                               const float* __restrict__ e2w,
                                               const float* __restrict__ e2b,
                                               float* __restrict__ agg2) {
    __shared__ float w_s[7 * HID];
    __shared__ float b_s[HID];
    __shared__ float Csm[64 * 129];
    __shared__ float ea_s[64 * 8];
    __shared__ int ss_s[64];
    __shared__ int ds_s[64];
    const int t = threadIdx.x;
    const int e0 = blockIdx.x * 64;
    for (int i = t; i < 7 * HID; i += 256) w_s[i] = e2w[i];
    if (t < HID) b_s[t] = e2b[t];
    if (t < 64) ss_s[t] = ss2[e0 + t];
    else if (t < 128) ds_s[t - 64] = ds2[e0 + (t - 64)];
    for (int i = t; i < 512; i += 256) ea_s[i] = eas[e0 * 8 + i];
    __syncthreads();

    const int r = t >> 2, c0 = (t & 3) * 32;
    const int s = ss_s[r];
    float eav[7];
#pragma unroll
    for (int q = 0; q < 7; ++q) eav[q] = ea_s[r * 8 + q];
    const s16x8* rp = (const s16x8*)&r1b[s * HID + c0];
#pragma unroll
    for (int u = 0; u < 4; ++u) {
        s16x8 hv = rp[u];
#pragma unroll
        for (int j = 0; j < 8; ++j) {
            const int c = c0 + u * 8 + j;
            float v = bf2f(hv[j]) + b_s[c];
#pragma unroll
            for (int q = 0; q < 7; ++q) v = fmaf(eav[q], w_s[q * HID + c], v);
            Csm[r * 129 + c] = fmaxf(v, 0.f);
        }
    }
    __syncthreads();
    if (t < 128) {
        float ssum = 0.f;
        int prev = ds_s[0];
        for (int rr = 0; rr < 64; ++rr) {
            const int d = ds_s[rr];
            const float v = Csm[rr * 129 + t];
            if (d != prev) { atomicAdd(&agg2[prev * HID + t], ssum); ssum = 0.f; prev = d; }
            ssum += v;
        }
        atomicAdd(&agg2[prev * HID + t], ssum);
    }
}

// -------- node MLP2: r2 = bf16(relu(relu((r1b+agg2)@V1 + b1)@V2 + b2)) -----
__global__ __launch_bounds__(256) void k_node2(const unsigned short* __restrict__ r1b,
                                               const float* __restrict__ agg2,
                                               const unsigned short* __restrict__ V1t,
                                               const unsigned short* __restrict__ V2t,
                                               const float* __restrict__ b1,
                                               const float* __restrict__ b2,
                                               unsigned short* __restrict__ r2) {
    __shared__ __align__(16) unsigned short Asm[64 * 40];
    __shared__ __align__(16) unsigned short Bsm[128 * 40];
    __shared__ __align__(16) unsigned short Hsm[64 * 136];
    const int t = threadIdx.x;
    const int i0 = blockIdx.x * 64;
    const int lane = t & 63, wid = t >> 6, wr = wid >> 1, wc = wid & 1;
    const int r = t >> 2, kc = (t & 3) * 8;
    const int rg = i0 + r;
    const bool rvalid = rg < N_NODES;

    f32x4 acc[2][4];
    const f32x4 zero = {0.f, 0.f, 0.f, 0.f};
#pragma unroll
    for (int mi = 0; mi < 2; ++mi)
#pragma unroll
        for (int ni = 0; ni < 4; ++ni) acc[mi][ni] = zero;

    for (int ks = 0; ks < 4; ++ks) {
        {
            const int kb = ks * 32 + kc;
            s16x8 v;
            if (rvalid) {
                const s16x8 ra = *(const s16x8*)&r1b[rg * HID + kb];
                const f32x4* pb = (const f32x4*)&agg2[rg * HID + kb];
                f32x4 w0 = pb[0], w1 = pb[1];
#pragma unroll
                for (int j = 0; j < 4; ++j) v[j] = (short)f2bf(bf2f(ra[j]) + w0[j]);
#pragma unroll
                for (int j = 0; j < 4; ++j) v[4 + j] = (short)f2bf(bf2f(ra[4 + j]) + w1[j]);
            } else {
#pragma unroll
                for (int j = 0; j < 8; ++j) v[j] = 0;
            }
            *(s16x8*)&Asm[r * 40 + kc] = v;
        }
        STAGE_B(Bsm, &V1t[ks * 32], HID);
        __syncthreads();
        const int koff = (lane >> 4) * 8;
        const int rA = lane & 15;
        s16x8 a0 = *(const s16x8*)&Asm[(wr * 32 + rA) * 40 + koff];
        s16x8 a1 = *(const s16x8*)&Asm[(wr * 32 + 16 + rA) * 40 + koff];
#pragma unroll
        for (int ni = 0; ni < 4; ++ni) {
            s16x8 b = *(const s16x8*)&Bsm[(wc * 64 + ni * 16 + rA) * 40 + koff];
            acc[0][ni] = __builtin_amdgcn_mfma_f32_16x16x32_bf16(a0, b, acc[0][ni], 0, 0, 0);
            acc[1][ni] = __builtin_amdgcn_mfma_f32_16x16x32_bf16(a1, b, acc[1][ni], 0, 0, 0);
        }
        __syncthreads();
    }
    const int jb = wc * 64 + (lane & 15);
#pragma unroll
    for (int mi = 0; mi < 2; ++mi) {
#pragma unroll
        for (int reg = 0; reg < 4; ++reg) {
            const int rloc = wr * 32 + mi * 16 + (lane >> 4) * 4 + reg;
            const int rowg = i0 + rloc;
#pragma unroll
            for (int ni = 0; ni < 4; ++ni) {
                const int j = jb + ni * 16;
                float v = acc[mi][ni][reg];
                if (rowg < N_NODES) {
                    v += b1[j];
                    v = fmaxf(v, 0.f);
                } else v = 0.f;
                Hsm[rloc * 136 + j] = f2bf(v);
            }
        }
    }
    __syncthreads();
    f32x4 acc2[2][4];
#pragma unroll
    for (int mi = 0; mi < 2; ++mi)
#pragma unroll
        for (int ni = 0; ni < 4; ++ni) acc2[mi][ni] = zero;

    for (int ks = 0; ks < 4; ++ks) {
        STAGE_B(Bsm, &V2t[ks * 32], HID);
        __syncthreads();
        const int koff = (lane >> 4) * 8;
        const int rA = lane & 15;
        s16x8 a0 = *(const s16x8*)&Hsm[(wr * 32 + rA) * 136 + ks * 32 + koff];
        s16x8 a1 = *(const s16x8*)&Hsm[(wr * 32 + 16 + rA) * 136 + ks * 32 + koff];
#pragma unroll
        for (int ni = 0; ni < 4; ++ni) {
            s16x8 b = *(const s16x8*)&Bsm[(wc * 64 + ni * 16 + rA) * 40 + koff];
            acc2[0][ni] = __builtin_amdgcn_mfma_f32_16x16x32_bf16(a0, b, acc2[0][ni], 0, 0, 0);
            acc2[1][ni] = __builtin_amdgcn_mfma_f32_16x16x32_bf16(a1, b, acc2[1][ni], 0, 0, 0);
        }
        __syncthreads();
    }
#pragma unroll
    for (int mi = 0; mi < 2; ++mi) {
#pragma unroll
        for (int reg = 0; reg < 4; ++reg) {
            const int rloc = wr * 32 + mi * 16 + (lane >> 4) * 4 + reg;
            const int rowg = i0 + rloc;
            if (rowg < N_NODES) {
#pragma unroll
                for (int ni = 0; ni < 4; ++ni) {
                    const int j = jb + ni * 16;
                    float v = acc2[mi][ni][reg] + b2[j];
                    r2[rowg * HID + j] = f2bf(fmaxf(v, 0.f));
                }
            }
        }
    }
}

// ------- edge head (original order): ea-part folded into MFMA acc-init -----
__global__ __launch_bounds__(256) void k_head(const unsigned short* __restrict__ r2,
                                              const int* __restrict__ srcp,
                                              const int* __restrict__ dstp,
                                              const float* __restrict__ ea,
                                              const unsigned short* __restrict__ EW1t,
                                              const unsigned short* __restrict__ EWeaT,
                                              const float* __restrict__ emw2,
                                              const float* __restrict__ emb2,
                                              float* __restrict__ out) {
    __shared__ __align__(16) unsigned short Asm[64 * 40];
    __shared__ __align__(16) unsigned short Bsm[128 * 40];
    __shared__ float Hsm[64 * 129];
    __shared__ float w2_s[256];
    __shared__ float b2_s[2];
    __shared__ int src_s[64];
    __shared__ int dst_s[64];
    __shared__ float red[512];
    const int t = threadIdx.x;
    const int e0 = blockIdx.x * 64;

    if (t < 256) w2_s[t] = emw2[t];
    if (t < 2) b2_s[t] = emb2[t];
    if (t < 64) src_s[t] = srcp[e0 + t];
    else if (t < 128) dst_s[t - 64] = dstp[e0 + (t - 64)];

    const int lane = t & 63, wid = t >> 6, wr = wid >> 1, wc = wid & 1;
    const int r = t >> 2, kc = (t & 3) * 8;
    const int rA = lane & 15;
    const int koff = (lane >> 4) * 8;

    // build eap tile [64][32]: cols 0..6 = ea, 7 = 1.0 (bias), rest 0
    {
        s16x8 v;
#pragma unroll
        for (int j = 0; j < 8; ++j) v[j] = 0;
        if (kc == 0) {
#pragma unroll
            for (int q = 0; q < 7; ++q) v[q] = (short)f2bf(ea[(e0 + r) * 7 + q]);
            v[7] = (short)0x3F80;   // 1.0 bf16
        }
        *(s16x8*)&Asm[r * 40 + kc] = v;
    }
    STAGE_B(Bsm, EWeaT, 32);
    __syncthreads();

    f32x4 acc[2][4];
    const f32x4 zero = {0.f, 0.f, 0.f, 0.f};
    {   // acc init = [ea|1] @ [em_w1_ea; emb1]
        const s16x8 eap0 = *(const s16x8*)&Asm[(wr * 32 + rA) * 40 + koff];
        const s16x8 eap1 = *(const s16x8*)&Asm[(wr * 32 + 16 + rA) * 40 + koff];
#pragma unroll
        for (int ni = 0; ni < 4; ++ni) {
            s16x8 b = *(const s16x8*)&Bsm[(wc * 64 + ni * 16 + rA) * 40 + koff];
            acc[0][ni] = __builtin_amdgcn_mfma_f32_16x16x32_bf16(eap0, b, zero, 0, 0, 0);
            acc[1][ni] = __builtin_amdgcn_mfma_f32_16x16x32_bf16(eap1, b, zero, 0, 0, 0);
        }
    }
    __syncthreads();

    for (int ks = 0; ks < 8; ++ks) {
        {
            const int k = ks * 32 + kc;
            const unsigned short* p = (k < HID) ? &r2[src_s[r] * HID + k]
                                                : &r2[dst_s[r] * HID + (k - HID)];
            *(s16x8*)&Asm[r * 40 + kc] = *(const s16x8*)p;
        }
        STAGE_B(Bsm, &EW1t[ks * 32], 256);
        __syncthreads();
        s16x8 a0 = *(const s16x8*)&Asm[(wr * 32 + rA) * 40 + koff];
        s16x8 a1 = *(const s16x8*)&Asm[(wr * 32 + 16 + rA) * 40 + koff];
#pragma unroll
        for (int ni = 0; ni < 4; ++ni) {
            s16x8 b = *(const s16x8*)&Bsm[(wc * 64 + ni * 16 + rA) * 40 + koff];
            acc[0][ni] = __builtin_amdgcn_mfma_f32_16x16x32_bf16(a0, b, acc[0][ni], 0, 0, 0);
            acc[1][ni] = __builtin_amdgcn_mfma_f32_16x16x32_bf16(a1, b, acc[1][ni], 0, 0, 0);
        }
        __syncthreads();
    }
    // layer1 epilogue: just relu -> Hsm (bias+ea already in acc)
    const int jb = wc * 64 + rA;
#pragma unroll
    for (int mi = 0; mi < 2; ++mi) {
#pragma unroll
        for (int reg = 0; reg < 4; ++reg) {
            const int rloc = wr * 32 + mi * 16 + (lane >> 4) * 4 + reg;
#pragma unroll
            for (int ni = 0; ni < 4; ++ni)
                Hsm[rloc * 129 + jb + ni * 16] = fmaxf(acc[mi][ni][reg], 0.f);
        }
    }
    __syncthreads();
    {
        const int e = t & 63, p = t >> 6;
        const float* hb = &Hsm[e * 129 + p * 32];
        float s0 = 0.f, s1 = 0.f;
#pragma unroll
        for (int j = 0; j < 32; ++j) {
            const float h = hb[j];
            s0 = fmaf(h, w2_s[(p * 32 + j) * 2], s0);
            s1 = fmaf(h, w2_s[(p * 32 + j) * 2 + 1], s1);
        }
        red[(e * 4 + p) * 2] = s0;
        red[(e * 4 + p) * 2 + 1] = s1;
    }
    __syncthreads();
    if (t < 64) {
        float o0 = b2_s[0], o1 = b2_s[1];
#pragma unroll
        for (int p = 0; p < 4; ++p) {
            o0 += red[(t * 4 + p) * 2];
            o1 += red[(t * 4 + p) * 2 + 1];
        }
        out[(e0 + t) * 2] = o0;
        out[(e0 + t) * 2 + 1] = o1;
    }
}

// ---------------------------------------------------------------------------
extern "C" void kernel_launch(void* const* d_in, const int* in_sizes, int n_in,
                              void* d_out, int out_size, void* d_ws, size_t ws_size,
                              hipStream_t stream) {
    (void)in_sizes; (void)n_in; (void)out_size; (void)ws_size;
    const float* x    = (const float*)d_in[0];
    const unsigned* eidx = (const unsigned*)d_in[1];
    const float* ea   = (const float*)d_in[2];
    const float* e1w  = (const float*)d_in[3];
    const float* e1b  = (const float*)d_in[4];
    const float* m1w1 = (const float*)d_in[5];
    const float* m1b1 = (const float*)d_in[6];
    const float* m1w2 = (const float*)d_in[7];
    const float* m1b2 = (const float*)d_in[8];
    const float* e2w  = (const float*)d_in[9];
    const float* e2b  = (const float*)d_in[10];
    const float* m2w1 = (const float*)d_in[11];
    const float* m2b1 = (const float*)d_in[12];
    const float* m2w2 = (const float*)d_in[13];
    const float* m2b2 = (const float*)d_in[14];
    const float* emw1 = (const float*)d_in[15];
    const float* emb1 = (const float*)d_in[16];
    const float* emw2 = (const float*)d_in[17];
    const float* emb2 = (const float*)d_in[18];
    float* out = (float*)d_out;

    char* ws = (char*)d_ws;
    float* yagg = (float*)(ws + 0);                            // 51.2 MB (conv1/conv2 agg)
    unsigned short* r1b = (unsigned short*)(ws + 51200000);    // 25.6 MB
    unsigned short* r2  = (unsigned short*)(ws + 76800000);    // 25.6 MB (aliases eas)
    float* eas          = (float*)(ws + 76800000);             // 19.2 MB (dead before r2 written)
    unsigned short* xbf = (unsigned short*)(ws + 102400000);   // 83.2 MB -> 185,600,000
    unsigned short* W1t   = (unsigned short*)(ws + 185600000); // 106,496
    unsigned short* W2t   = (unsigned short*)(ws + 185706496); // 32,768
    unsigned short* V1t   = (unsigned short*)(ws + 185739264); // 32,768
    unsigned short* V2t   = (unsigned short*)(ws + 185772032); // 32,768
    unsigned short* EW1t  = (unsigned short*)(ws + 185804800); // 65,536
    unsigned short* E1T   = (unsigned short*)(ws + 185870336); // 26,624
    unsigned short* EWeaT = (unsigned short*)(ws + 185896960); // 8,192 -> 185,905,152
    int* s32  = (int*)(ws + 185905152);                        // 2.4 MB
    int* d32  = (int*)(ws + 188305152);                        // 2.4 MB
    int* ss2  = (int*)(ws + 190705152);                        // 2.4 MB
    int* ds2  = (int*)(ws + 193105152);                        // 2.4 MB
    int* cnt  = (int*)(ws + 195505152);                        // 400 KB
    int* bsum = (int*)(ws + 195905152);                        // 4 KB

    hipMemsetAsync(yagg, 0, (size_t)N_NODES * HID * 4, stream);
    hipMemsetAsync(cnt, 0, (size_t)N_NODES * 4, stream);
    k_decode<<<2344, 256, 0, stream>>>(eidx, s32, d32);
    k_prep<<<596, 256, 0, stream>>>(m1w1, m1w2, m2w1, m2w2, emw1, e1w, e1b, emb1,
                                    W1t, W2t, V1t, V2t, EW1t, E1T, EWeaT);
    k_castx<<<(N_NODES * 52 + 255) / 256, 256, 0, stream>>>(x, xbf);
    k_hist<<<2344, 256, 0, stream>>>(d32, cnt);
    k_scanA<<<NB_SCAN, 256, 0, stream>>>(cnt, bsum);
    k_scanC<<<NB_SCAN, 256, 0, stream>>>(cnt, bsum);
    k_scatter<<<2344, 256, 0, stream>>>(s32, d32, ea, cnt, ss2, ds2, eas);
    k_edge1<<<N_EDGES / 64, 256, 0, stream>>>(xbf, ss2, ds2, eas, E1T, W1t, yagg);
    k_node1<<<(N_NODES + 63) / 64, 256, 0, stream>>>(xbf, yagg, W1t, W2t, m1b1, m1b2, r1b);
    hipMemsetAsync(yagg, 0, (size_t)N_NODES * HID * 4, stream);
    k_edge2<<<N_EDGES / 64, 256, 0, stream>>>(r1b, ss2, ds2, eas, e2w, e2b, yagg);
    k_node2<<<(N_NODES + 63) / 64, 256, 0, stream>>>(r1b, yagg, V1t, V2t, m2b1, m2b2, r2);
    k_head<<<N_EDGES / 64, 256, 0, stream>>>(r2, s32, d32, ea, EW1t, EWeaT,
                                             emw2, emb2, out);
}